// Round 6
// baseline (2160.917 us; speedup 1.0000x reference)
//
#include <hip/hip_runtime.h>
#include <hip/hip_bf16.h>

#define N_NODE 200000
#define EMB 100
#define NNZ 1000000
#define BATCH 1024
#define SLEN 50
#define BE (BATCH * EMB)
#define PROJ_ROWS 8
#define UNR 8
#define CSR_BLOCKS 1024
#define CSR_THREADS (CSR_BLOCKS * 256)
#define SCAN_CHUNKS 196        // ceil(N_NODE/1024)
#define DS_BLOCKS 768          // 3 blocks/CU at 47.7KB LDS

#define OFF_LC    20000000LL
#define OFF_NB    20102400LL
#define OFF_LOSS  20204800LL

typedef __hip_bfloat16 bf16;

__device__ __forceinline__ float b2f(bf16 x) { return __bfloat162float(x); }
__device__ __forceinline__ bf16 f2b(float x) { return __float2bfloat16(x); }

__device__ __forceinline__ float ldf(const void* p, long long i, int f32) {
    return f32 ? ((const float*)p)[i] : b2f(((const bf16*)p)[i]);
}
__device__ __forceinline__ void stf(void* p, long long i, int f32, float v) {
    if (f32) ((float*)p)[i] = v;
    else     ((bf16*)p)[i] = f2b(v);
}

// ---- paired (2-element) helpers: pair index pi covers elements 2pi, 2pi+1 ----
__device__ __forceinline__ float bfb2f(unsigned short s) {
    return __uint_as_float(((unsigned)s) << 16);
}
__device__ __forceinline__ unsigned short f2bfb(float x) {
    bf16 h = f2b(x); unsigned short r; __builtin_memcpy(&r, &h, 2); return r;
}
__device__ __forceinline__ float2 up2(unsigned u) {
    return make_float2(bfb2f((unsigned short)(u & 0xffff)), bfb2f((unsigned short)(u >> 16)));
}
__device__ __forceinline__ unsigned pk2(float a, float b) {
    return (unsigned)f2bfb(a) | ((unsigned)f2bfb(b) << 16);
}
__device__ __forceinline__ float2 ldf2(const void* p, long long pi, int f32) {
    if (f32) return ((const float2*)p)[pi];
    return up2(((const unsigned*)p)[pi]);
}
template<bool F32>
__device__ __forceinline__ float2 ldf2t(const void* p, long long pi) {
    if (F32) return ((const float2*)p)[pi];
    return up2(((const unsigned*)p)[pi]);
}
__device__ __forceinline__ void stf2(void* p, long long pi, int f32, float a, float b) {
    if (f32) ((float2*)p)[pi] = make_float2(a, b);
    else     ((unsigned*)p)[pi] = pk2(a, b);
}

__device__ __forceinline__ float wave_allreduce_sum(float v) {
    for (int m = 32; m > 0; m >>= 1) v += __shfl_xor(v, m, 64);
    return v;
}

// device-wide barrier: all blocks of the grid must be co-resident (caller ensures).
// slot must be zeroed before kernel start (memset each replay).
__device__ __forceinline__ void devbar(int* slot, int nb) {
    __syncthreads();
    if (threadIdx.x == 0) {
        __hip_atomic_fetch_add(slot, 1, __ATOMIC_ACQ_REL, __HIP_MEMORY_SCOPE_AGENT);
        while (__hip_atomic_load(slot, __ATOMIC_ACQUIRE, __HIP_MEMORY_SCOPE_AGENT) < nb)
            __builtin_amdgcn_s_sleep(2);
    }
    __syncthreads();
}

// ================= fused CSR build: hist+repack | scan | permute ==============
__global__ __launch_bounds__(256) void csr_build(
        const int* __restrict__ arow, const int* __restrict__ acol,
        const void* __restrict__ aval,
        int* __restrict__ counts,          // aliased as cursor after scan
        int2* __restrict__ bc, int2* __restrict__ cv,
        int* __restrict__ flag, int* __restrict__ gtot, int* __restrict__ bar,
        const void* __restrict__ emb, void* __restrict__ embp,
        int f32h, int use_pad) {
    __shared__ int ss[256];
    __shared__ int basesh;
    int t = threadIdx.x, blk = blockIdx.x;
    int tid = blk * 256 + t;

    // ---- phase 1: dtype sniff + hist (4 edges/thread) + repack emb ----
    if (tid == 0) {
        int f = 0;
        const bf16* p = (const bf16*)aval;
        for (int i = 0; i < 64; i++) {
            float x = b2f(p[i]);
            if (!(x >= 0.0f && x <= 1.0f)) f = 1;
        }
        *flag = f;
    }
    int e0 = tid * 4;
    if (e0 < NNZ) {
        int4 r4 = *(const int4*)&arow[e0];
        atomicAdd(&counts[r4.x], 1);
        atomicAdd(&counts[r4.y], 1);
        atomicAdd(&counts[r4.z], 1);
        atomicAdd(&counts[r4.w], 1);
    }
    if (use_pad) {
        for (long long idx = tid; idx < (long long)N_NODE * 16; idx += CSR_THREADS) {
            long long r = idx >> 4;
            int l0 = (int)(idx & 15) * 4;
            #pragma unroll
            for (int j = 0; j < 4; j++) {
                int l = l0 + j;
                float2 v = make_float2(0.f, 0.f);
                if (l < 50) v = ldf2(emb, r * 50 + l, f32h);
                stf2(embp, r * 64 + l, f32h, v.x, v.y);
            }
        }
    }
    devbar(&bar[0], CSR_BLOCKS);

    // ---- phase 2: one-pass scan (blocks 0..195, 1024 counts each, 4/thread) ----
    if (blk < SCAN_CHUNKS) {
        int i0 = blk * 1024 + t * 4;
        int v0 = 0, v1 = 0, v2 = 0, v3 = 0;
        if (i0 + 0 < N_NODE) v0 = counts[i0 + 0];
        if (i0 + 1 < N_NODE) v1 = counts[i0 + 1];
        if (i0 + 2 < N_NODE) v2 = counts[i0 + 2];
        if (i0 + 3 < N_NODE) v3 = counts[i0 + 3];
        int ts = v0 + v1 + v2 + v3;
        ss[t] = ts;
        __syncthreads();
        for (int off = 1; off < 256; off <<= 1) {
            int add = (t >= off) ? ss[t - off] : 0;
            __syncthreads();
            ss[t] += add;
            __syncthreads();
        }
        if (t == 255) basesh = atomicAdd(gtot, ss[255]);
        __syncthreads();
        int ex = basesh + ss[t] - ts;
        if (i0 + 0 < N_NODE) { counts[i0+0] = ex; bc[i0+0] = make_int2(ex, v0); ex += v0; }
        if (i0 + 1 < N_NODE) { counts[i0+1] = ex; bc[i0+1] = make_int2(ex, v1); ex += v1; }
        if (i0 + 2 < N_NODE) { counts[i0+2] = ex; bc[i0+2] = make_int2(ex, v2); ex += v2; }
        if (i0 + 3 < N_NODE) { counts[i0+3] = ex; bc[i0+3] = make_int2(ex, v3); }
    }
    devbar(&bar[1], CSR_BLOCKS);

    // ---- phase 3: permute edges (grid-stride), zero cv pad ----
    if (tid < 8) cv[NNZ + tid] = make_int2(0, 0);
    const int f32 = *flag;
    for (int e = tid; e < NNZ; e += CSR_THREADS) {
        int r = arow[e];
        int pos = atomicAdd(&counts[r], 1);
        float v = ldf(aval, e, f32);
        cv[pos] = make_int2(acol[e], __float_as_int(v));
    }
}

// ================= SpMM: wave per row, vectorizable cv loads (r5 proven) ======
__device__ __forceinline__ void ld_cv8(int2* c, const int2* __restrict__ cv, int k0) {
    #pragma unroll
    for (int j = 0; j < UNR; j++) c[j] = cv[k0 + j];   // unconditional, mergeable
}

template<bool F32>
__device__ __forceinline__ void spmm1_body(
        const int2* __restrict__ bc, const int2* __restrict__ cv,
        const void* __restrict__ src, int estride, unsigned* __restrict__ h1) {
    int lane = threadIdx.x & 63;
    int r = blockIdx.x * 4 + (threadIdx.x >> 6);
    if (r >= N_NODE) return;
    bool act = lane < 50;
    int pl = (estride == 64) ? lane : (act ? lane : 0);
    int2 b = bc[r];
    int k0 = b.x, k1 = b.x + b.y;
    int2 c[UNR];
    ld_cv8(c, cv, k0);
    int c0x = c[0].x;
    float2 e[UNR];
    #pragma unroll
    for (int j = 0; j < UNR; j++) {
        int cl = (k0 + j < k1) ? c[j].x : c0x;       // clamp in registers, same line
        e[j] = ldf2t<F32>(src, (long long)cl * estride + pl);
    }
    float a0 = 0.f, a1 = 0.f;
    #pragma unroll
    for (int j = 0; j < UNR; j++) {
        float v = (k0 + j < k1) ? __int_as_float(c[j].y) : 0.f;
        a0 += v * e[j].x; a1 += v * e[j].y;
    }
    for (int k = k0 + UNR; k < k1; k += UNR) {       // rare tail (deg > 8)
        int2 ct[UNR];
        #pragma unroll
        for (int j = 0; j < UNR; j++) { int kk = k + j; ct[j] = cv[kk < k1 ? kk : k1 - 1]; }
        float2 et[UNR];
        #pragma unroll
        for (int j = 0; j < UNR; j++)
            et[j] = ldf2t<F32>(src, (long long)ct[j].x * estride + pl);
        #pragma unroll
        for (int j = 0; j < UNR; j++) {
            float v = (k + j < k1) ? __int_as_float(ct[j].y) : 0.f;
            a0 += v * et[j].x; a1 += v * et[j].y;
        }
    }
    h1[(long long)r * 64 + lane] = pk2(a0, a1);      // full-wave 256B aligned store
}

__global__ __launch_bounds__(256) void spmm_gather1(
        const int2* __restrict__ bc, const int2* __restrict__ cv,
        const void* __restrict__ src, int estride,
        unsigned* __restrict__ h1, const int* __restrict__ flagp) {
    if (*flagp) spmm1_body<true>(bc, cv, src, estride, h1);
    else        spmm1_body<false>(bc, cv, src, estride, h1);
}

template<bool F32>
__device__ __forceinline__ void spmm2_body(
        const int2* __restrict__ bc, const int2* __restrict__ cv,
        const void* __restrict__ emb,
        const unsigned* __restrict__ h1, void* __restrict__ out) {
    int lane = threadIdx.x & 63;
    int r = blockIdx.x * 4 + (threadIdx.x >> 6);
    if (r >= N_NODE) return;
    bool act = lane < 50;
    int pl = act ? lane : 0;
    int2 b = bc[r];
    int k0 = b.x, k1 = b.x + b.y;
    int2 c[UNR];
    ld_cv8(c, cv, k0);
    int c0x = c[0].x;
    float2 ebv = ldf2t<F32>(emb, (long long)r * 50 + pl);
    float2 h1r = up2(h1[(long long)r * 64 + lane]);
    float2 e[UNR];
    #pragma unroll
    for (int j = 0; j < UNR; j++) {
        int cl = (k0 + j < k1) ? c[j].x : c0x;
        e[j] = up2(h1[(long long)cl * 64 + lane]);   // padded aligned gather
    }
    float a0 = 0.f, a1 = 0.f;
    #pragma unroll
    for (int j = 0; j < UNR; j++) {
        float v = (k0 + j < k1) ? __int_as_float(c[j].y) : 0.f;
        a0 += v * e[j].x; a1 += v * e[j].y;
    }
    for (int k = k0 + UNR; k < k1; k += UNR) {       // rare tail
        int2 ct[UNR];
        #pragma unroll
        for (int j = 0; j < UNR; j++) { int kk = k + j; ct[j] = cv[kk < k1 ? kk : k1 - 1]; }
        float2 et[UNR];
        #pragma unroll
        for (int j = 0; j < UNR; j++)
            et[j] = up2(h1[(long long)ct[j].x * 64 + lane]);
        #pragma unroll
        for (int j = 0; j < UNR; j++) {
            float v = (k + j < k1) ? __int_as_float(ct[j].y) : 0.f;
            a0 += v * et[j].x; a1 += v * et[j].y;
        }
    }
    if (act)
        stf2(out, (long long)r * 50 + lane, F32 ? 1 : 0,
             (ebv.x + h1r.x + a0) * (1.0f / 3.0f), (ebv.y + h1r.y + a1) * (1.0f / 3.0f));
}

__global__ __launch_bounds__(256) void spmm_gather2(
        const int2* __restrict__ bc, const int2* __restrict__ cv,
        const void* __restrict__ emb,
        const unsigned* __restrict__ h1, void* __restrict__ out,
        const int* __restrict__ flagp) {
    if (*flagp) spmm2_body<true>(bc, cv, emb, h1, out);
    else        spmm2_body<false>(bc, cv, emb, h1, out);
}

// ================= downstream device bodies (no early returns!) ===============
__device__ void rel_rows_dev(const void* __restrict__ out, const int* __restrict__ items,
                             const void* __restrict__ slen, float* __restrict__ rel,
                             int f32, int blk) {
    int lane = threadIdx.x & 63;
    int b = blk * 4 + (threadIdx.x >> 6);
    if (lane < 50) {
        float s0 = 0.f, s1 = 0.f;
        #pragma unroll
        for (int l0 = 0; l0 < SLEN; l0 += 10) {
            int it[10];
            #pragma unroll
            for (int j = 0; j < 10; j++) it[j] = items[b * SLEN + l0 + j];
            float2 e[10];
            #pragma unroll
            for (int j = 0; j < 10; j++) {
                int idx = (it[j] > 0) ? it[j] - 1 : 0;
                e[j] = ldf2(out, (long long)idx * 50 + lane, f32);
            }
            #pragma unroll
            for (int j = 0; j < 10; j++) {
                float m = (it[j] > 0) ? 1.f : 0.f;
                s0 += m * e[j].x; s1 += m * e[j].y;
            }
        }
        float inv = 1.0f / ldf(slen, b, f32);
        ((float2*)rel)[b * 50 + lane] = make_float2(s0 * inv, s1 * inv);
    }
}

__device__ void bmm0_dev(float* smem, const void* __restrict__ M,
                         const float* __restrict__ X, float* __restrict__ Y,
                         int f32, int blk) {
    float (*ms)[BATCH] = (float(*)[BATCH])smem;
    int i0 = blk * 4;
    int t = threadIdx.x;
    for (int idx = t; idx < 4 * BATCH; idx += 256) {
        int rr = idx >> 10, j = idx & 1023;
        ms[rr][j] = ldf(M, (long long)(i0 + rr) * BATCH + j, f32);
    }
    __syncthreads();
    int w = t >> 6, lane = t & 63;
    if (lane < 50) {
        int i = i0 + w;
        const float2* X2 = (const float2*)X;
        float s0 = 0.f, s1 = 0.f;
        for (int j = 0; j < BATCH; j++) {
            float m = ms[w][j];
            float2 x = X2[j * 50 + lane];
            s0 += m * x.x; s1 += m * x.y;
        }
        ((float2*)Y)[i * 50 + lane] = make_float2(s0, s1);
    }
}

// projector: Z = (ELU(X@W1^T+b1))@W2^T+b2, row norm, opt transpose
__device__ void proj_dev(float* smem, const void* __restrict__ X, int x_dual,
                         const void* __restrict__ W1, const void* __restrict__ B1,
                         const void* __restrict__ W2, const void* __restrict__ B2,
                         float* __restrict__ Z, float* __restrict__ ZT,
                         float* __restrict__ nrm, int f32, int blk) {
    float* wT = smem;                               // 10000
    float* bsh = smem + 10000;                      // 100
    float (*hid)[EMB] = (float(*)[EMB])(smem + 10100);  // 800
    float (*xr)[EMB]  = (float(*)[EMB])(smem + 10900);  // 200
    float (*red2)[2]  = (float(*)[2])(smem + 11100);    // 4
    int t = threadIdx.x;
    int sub = t >> 7, u = t & 127;
    int r0 = blk * PROJ_ROWS;
    for (int idx = t; idx < EMB * EMB; idx += 256) {
        int o = idx / EMB, k = idx - o * EMB;
        wT[k * EMB + o] = ldf(W1, idx, f32);
    }
    if (t < EMB) bsh[t] = ldf(B1, t, f32);
    __syncthreads();
    for (int pr = 0; pr < PROJ_ROWS; pr += 2) {
        int row = r0 + pr + sub;
        if (u < EMB)
            xr[sub][u] = x_dual ? ldf(X, (long long)row * EMB + u, f32)
                                : ((const float*)X)[row * EMB + u];
        __syncthreads();
        if (u < EMB) {
            float s = bsh[u];
            for (int k = 0; k < EMB; k++) s += xr[sub][k] * wT[k * EMB + u];
            hid[pr + sub][u] = (s > 0.f) ? s : expm1f(s);
        }
        __syncthreads();
    }
    for (int idx = t; idx < EMB * EMB; idx += 256) {
        int o = idx / EMB, k = idx - o * EMB;
        wT[k * EMB + o] = ldf(W2, idx, f32);
    }
    if (t < EMB) bsh[t] = ldf(B2, t, f32);
    __syncthreads();
    for (int pr = 0; pr < PROJ_ROWS; pr += 2) {
        int row = r0 + pr + sub;
        float sq = 0.f;
        if (u < EMB) {
            float o = bsh[u];
            const float* h = hid[pr + sub];
            for (int k = 0; k < EMB; k++) o += h[k] * wT[k * EMB + u];
            Z[(long long)row * EMB + u] = o;
            if (ZT) ZT[(long long)u * BATCH + row] = o;
            sq = o * o;
        }
        sq = wave_allreduce_sum(sq);
        if ((t & 63) == 0) red2[sub][(t >> 6) & 1] = sq;
        __syncthreads();
        if (u == 0) nrm[row] = sqrtf(red2[sub][0] + red2[sub][1]);
        __syncthreads();
    }
}

// projector for z1 fused with its 8 loss rows (z1p/n1 stay in LDS)
__device__ void proj_loss_dev(float* smem, const float* __restrict__ X,
                              const void* __restrict__ W1, const void* __restrict__ B1,
                              const void* __restrict__ W2, const void* __restrict__ B2,
                              const float* __restrict__ z2pT, const float* __restrict__ n2,
                              float* __restrict__ lacc, int* __restrict__ done,
                              void* __restrict__ out, int f32, int blk) {
    float* wT = smem;                               // 10000
    float* bsh = smem + 10000;                      // 100
    float (*hid)[EMB] = (float(*)[EMB])(smem + 10100);  // 800
    float (*xr)[EMB]  = (float(*)[EMB])(smem + 10900);  // 200
    float (*red2)[2]  = (float(*)[2])(smem + 11100);    // 4
    float (*zsh)[EMB] = (float(*)[EMB])(smem + 11104);  // 800
    float* n1sh = smem + 11904;                     // 8
    float* sd   = smem + 11912;                     // 1
    float* red  = smem + 11913;                     // 4
    int t = threadIdx.x;
    int sub = t >> 7, u = t & 127;
    int r0 = blk * PROJ_ROWS;
    for (int idx = t; idx < EMB * EMB; idx += 256) {
        int o = idx / EMB, k = idx - o * EMB;
        wT[k * EMB + o] = ldf(W1, idx, f32);
    }
    if (t < EMB) bsh[t] = ldf(B1, t, f32);
    __syncthreads();
    for (int pr = 0; pr < PROJ_ROWS; pr += 2) {
        int row = r0 + pr + sub;
        if (u < EMB) xr[sub][u] = X[(long long)row * EMB + u];
        __syncthreads();
        if (u < EMB) {
            float s = bsh[u];
            for (int k = 0; k < EMB; k++) s += xr[sub][k] * wT[k * EMB + u];
            hid[pr + sub][u] = (s > 0.f) ? s : expm1f(s);
        }
        __syncthreads();
    }
    for (int idx = t; idx < EMB * EMB; idx += 256) {
        int o = idx / EMB, k = idx - o * EMB;
        wT[k * EMB + o] = ldf(W2, idx, f32);
    }
    if (t < EMB) bsh[t] = ldf(B2, t, f32);
    __syncthreads();
    for (int pr = 0; pr < PROJ_ROWS; pr += 2) {
        float sq = 0.f;
        float o = 0.f;
        if (u < EMB) {
            o = bsh[u];
            const float* h = hid[pr + sub];
            for (int k = 0; k < EMB; k++) o += h[k] * wT[k * EMB + u];
            sq = o * o;
        }
        __syncthreads();              // all reads of hid[pr+sub] done
        if (u < EMB) zsh[pr + sub][u] = o;
        sq = wave_allreduce_sum(sq);
        if ((t & 63) == 0) red2[sub][(t >> 6) & 1] = sq;
        __syncthreads();
        if (u == 0) n1sh[pr + sub] = sqrtf(red2[sub][0] + red2[sub][1]);
        __syncthreads();
    }
    float blockloss = 0.f;
    for (int rr = 0; rr < PROJ_ROWS; rr++) {
        int i = r0 + rr;
        float ni = n1sh[rr];
        float d0 = 0.f, d1 = 0.f, d2 = 0.f, d3 = 0.f;
        for (int k = 0; k < EMB; k++) {
            float zv = zsh[rr][k];
            const float* row = z2pT + k * BATCH;
            d0 += zv * row[t];
            d1 += zv * row[t + 256];
            d2 += zv * row[t + 512];
            d3 += zv * row[t + 768];
        }
        float e0 = expf(d0 / (ni * n2[t]) * 5.0f);
        float e1 = expf(d1 / (ni * n2[t + 256]) * 5.0f);
        float e2 = expf(d2 / (ni * n2[t + 512]) * 5.0f);
        float e3 = expf(d3 / (ni * n2[t + 768]) * 5.0f);
        if (t == (i & 255)) {
            int m = i >> 8;
            sd[0] = (m == 0) ? e0 : (m == 1) ? e1 : (m == 2) ? e2 : e3;
        }
        float local = e0 + e1 + e2 + e3;
        float w = wave_allreduce_sum(local);
        if ((t & 63) == 0) red[t >> 6] = w;
        __syncthreads();
        if (t == 0) {
            float S = red[0] + red[1] + red[2] + red[3];
            blockloss += -logf(sd[0] / (S + 1e-8f));
        }
        __syncthreads();
    }
    if (t == 0) {
        atomicAdd(lacc, blockloss * (1.0f / BATCH));
        __threadfence();
        int old = atomicAdd(done, 1);
        if (old == BATCH / PROJ_ROWS - 1) {
            float v = atomicAdd(lacc, 0.0f);   // fully-merged value
            stf(out, OFF_LOSS, f32, v);
        }
    }
}

__device__ void bmm2_selu_dev(float* smem, const void* __restrict__ M,
                              const float* __restrict__ X,
                              float* __restrict__ sess, float* __restrict__ sessT,
                              float* __restrict__ ns, void* __restrict__ out,
                              int f32, int blk) {
    float (*ms)[BATCH] = (float(*)[BATCH])smem;
    int i0 = blk * 4;
    int t = threadIdx.x;
    for (int idx = t; idx < 4 * BATCH; idx += 256) {
        int rr = idx >> 10, j = idx & 1023;
        ms[rr][j] = ldf(M, (long long)(i0 + rr) * BATCH + j, f32);
    }
    __syncthreads();
    int w = t >> 6, lane = t & 63;
    bool act = lane < 50;
    int i = i0 + w;
    float s0 = 0.f, s1 = 0.f;
    if (act) {
        const float2* X2 = (const float2*)X;
        for (int j = 0; j < BATCH; j++) {
            float m = ms[w][j];
            float2 x = X2[j * 50 + lane];
            s0 += m * x.x; s1 += m * x.y;
        }
    }
    const float sc = 1.0507009873554804934193349852946f;
    const float al = 1.6732632423543772848170429916717f;
    float c0 = (s0 > 0.f) ? sc * s0 : sc * (al * expm1f(s0));
    float c1 = (s1 > 0.f) ? sc * s1 : sc * (al * expm1f(s1));
    if (!act) { c0 = 0.f; c1 = 0.f; }
    float nrm = sqrtf(wave_allreduce_sum(c0 * c0 + c1 * c1));
    float l0 = c0 / nrm, l1 = c1 / nrm;
    float nterm = act ? (l0 * l0 + l1 * l1 + 2e-6f) : 0.f;
    float n2sum = wave_allreduce_sum(nterm);
    if (act) {
        ((float2*)sess)[i * 50 + lane] = make_float2(l0, l1);
        sessT[(2 * lane) * BATCH + i] = l0;
        sessT[(2 * lane + 1) * BATCH + i] = l1;
        stf2(out, OFF_LC / 2 + (long long)i * 50 + lane, f32, l0, l1);
    }
    if (lane == 0) ns[i] = sqrtf(n2sum);
}

__device__ void neighbor_dev(float* smem, const float* __restrict__ sess,
                             const float* __restrict__ sessT, const float* __restrict__ ns,
                             void* __restrict__ out, int f32, int i) {
    float* si  = smem;                 // 100
    float* red = smem + 100;           // 4
    float* wrv = smem + 104;           // 4
    int*   wri = (int*)(smem + 108);   // 4
    float* chv = smem + 112;           // 3
    int*   chi = (int*)(smem + 115);   // 3
    float* stv = smem + 118;           // 3
    int t = threadIdx.x;   // 256 threads
    if (t < EMB) si[t] = sess[i * EMB + t];
    __syncthreads();
    float ni = ns[i];
    float d0 = 0.f, d1 = 0.f, d2 = 0.f, d3 = 0.f;
    for (int k = 0; k < EMB; k++) {
        float sv = si[k];
        const float* row = sessT + k * BATCH;
        d0 += sv * row[t];
        d1 += sv * row[t + 256];
        d2 += sv * row[t + 512];
        d3 += sv * row[t + 768];
    }
    float pv0 = expf(d0 / (ni * ns[t]));
    float pv1 = expf(d1 / (ni * ns[t + 256]));
    float pv2 = expf(d2 / (ni * ns[t + 512]));
    float pv3 = expf(d3 / (ni * ns[t + 768]));
    float local = pv0 + pv1 + pv2 + pv3;
    float w = wave_allreduce_sum(local);
    if ((t & 63) == 0) red[t >> 6] = w;
    __syncthreads();
    float S = red[0] + red[1] + red[2] + red[3];

    int c0 = -1, c1 = -1, c2 = -1;
    float pv[4] = {pv0, pv1, pv2, pv3};
    for (int r = 0; r < 3; r++) {
        float bv = -1e30f; int bi = 0x7fffffff;
        #pragma unroll
        for (int m = 0; m < 4; m++) {
            int j = t + (m << 8);
            if (j == c0 || j == c1 || j == c2) continue;
            float v = pv[m];
            if (v > bv || (v == bv && j < bi)) { bv = v; bi = j; }
        }
        #pragma unroll
        for (int off = 1; off < 64; off <<= 1) {
            float ov = __shfl_xor(bv, off);
            int oi = __shfl_xor(bi, off);
            if (ov > bv || (ov == bv && oi < bi)) { bv = ov; bi = oi; }
        }
        if ((t & 63) == 0) { wrv[t >> 6] = bv; wri[t >> 6] = bi; }
        __syncthreads();
        if (t == 0) {
            float fv = wrv[0]; int fi = wri[0];
            for (int wq = 1; wq < 4; wq++) {
                if (wrv[wq] > fv || (wrv[wq] == fv && wri[wq] < fi)) { fv = wrv[wq]; fi = wri[wq]; }
            }
            chv[r] = fv; chi[r] = fi;
        }
        __syncthreads();
        if (r == 0) c0 = chi[0];
        else if (r == 1) c1 = chi[1];
        else c2 = chi[2];
    }
    if (t == 0) {
        float e0 = expf(chv[0] / S), e1 = expf(chv[1] / S), e2 = expf(chv[2] / S);
        float es = e0 + e1 + e2;
        stv[0] = e0 / es; stv[1] = e1 / es; stv[2] = e2 / es;
    }
    __syncthreads();
    if (t < EMB) {
        float o = stv[0] * sess[chi[0] * EMB + t]
                + stv[1] * sess[chi[1] * EMB + t]
                + stv[2] * sess[chi[2] * EMB + t];
        stf(out, OFF_NB + i * EMB + t, f32, o);
    }
}

// ============ fused downstream: rel | bmm1+projz2 | bmm2+selu | neigh+projz1+loss
__global__ __launch_bounds__(256, 3) void downstream(
        void* __restrict__ out, const int* __restrict__ items,
        const void* __restrict__ slen, float* __restrict__ rel,
        const void* __restrict__ Amat, float* __restrict__ t1,
        const void* __restrict__ z2,
        const void* __restrict__ Wkg1, const void* __restrict__ bkg1,
        const void* __restrict__ Wkg2, const void* __restrict__ bkg2,
        float* __restrict__ z2p, float* __restrict__ z2pT, float* __restrict__ n2,
        const void* __restrict__ Dmat,
        float* __restrict__ sess, float* __restrict__ sessT, float* __restrict__ ns,
        const void* __restrict__ Wcf1, const void* __restrict__ bcf1,
        const void* __restrict__ Wcf2, const void* __restrict__ bcf2,
        float* __restrict__ lacc, int* __restrict__ done2, int* __restrict__ bar,
        const int* __restrict__ flagp) {
    __shared__ float smem[11920];
    const int f32 = *flagp;
    int blk = blockIdx.x;

    // P0: rel_rows (work 256)
    for (int w = blk; w < 256; w += DS_BLOCKS)
        rel_rows_dev(out, items, slen, rel, f32, w);
    devbar(&bar[4], DS_BLOCKS);

    // P1: bmm1 (256) + proj(z2) (128)
    for (int w = blk; w < 384; w += DS_BLOCKS) {
        if (w < 256) bmm0_dev(smem, Amat, rel, t1, f32, w);
        else proj_dev(smem, z2, 1, Wkg1, bkg1, Wkg2, bkg2, z2p, z2pT, n2, f32, w - 256);
    }
    devbar(&bar[5], DS_BLOCKS);

    // P2: bmm2 + selu + norm (256); also zero loss accumulators for P3
    if (blk == 0 && threadIdx.x == 0) { *lacc = 0.f; *done2 = 0; }
    for (int w = blk; w < 256; w += DS_BLOCKS)
        bmm2_selu_dev(smem, Dmat, t1, sess, sessT, ns, out, f32, w);
    devbar(&bar[6], DS_BLOCKS);

    // P3: neighbor (1024) + proj(z1)+loss (128)
    for (int w = blk; w < 1152; w += DS_BLOCKS) {
        __syncthreads();    // protect smem reuse across iterations
        if (w < 1024) neighbor_dev(smem, sess, sessT, ns, out, f32, w);
        else proj_loss_dev(smem, sess, Wcf1, bcf1, Wcf2, bcf2, z2pT, n2,
                           lacc, done2, out, f32, w - 1024);
    }
}

extern "C" void kernel_launch(void* const* d_in, const int* in_sizes, int n_in,
                              void* d_out, int out_size, void* d_ws, size_t ws_size,
                              hipStream_t stream) {
    const void* emb  = d_in[0];
    const void* aval = d_in[1];
    const void* Amat = d_in[2];
    const void* Dmat = d_in[3];
    const void* z2   = d_in[4];
    const void* Wcf1 = d_in[5];
    const void* bcf1 = d_in[6];
    const void* Wcf2 = d_in[7];
    const void* bcf2 = d_in[8];
    const void* Wkg1 = d_in[9];
    const void* bkg1 = d_in[10];
    const void* Wkg2 = d_in[11];
    const void* bkg2 = d_in[12];
    const void* slen = d_in[13];
    const int* arow  = (const int*)d_in[14];
    const int* acol  = (const int*)d_in[15];
    const int* items = (const int*)d_in[16];

    // dtype from host-visible byte size (exact match only; else no padding)
    long long esz = in_sizes ? (long long)in_sizes[0] : 0;
    int f32_host = (esz == (long long)N_NODE * EMB * 4) ? 1 : 0;
    int known_dtype = (esz == (long long)N_NODE * EMB * 2) || f32_host;

    // ---- workspace layout ----
    int* flag      = (int*)d_ws;                       // +0
    int* gtot      = (int*)((char*)d_ws + 16);         // +16
    int* bar       = (int*)((char*)d_ws + 32);         // +32 .. +63 (8 slots)
    int* counts    = (int*)((char*)d_ws + 256);        // N_NODE (aliased as cursor)
    int2* bc       = (int2*)(counts + N_NODE);         // N_NODE (base,count)
    int2* cv       = bc + N_NODE;                      // NNZ+8 packed (col,val)
    unsigned* h1buf = (unsigned*)(cv + NNZ + 8);       // N_NODE*64 pairs, padded (51.2MB)
    char* tailbase = (char*)(h1buf + (long long)N_NODE * 64);
    // emb_pad (only live during repack+spmm1) aliases the small-buffer region
    void* emb_pad  = (void*)tailbase;
    long long embpad_bytes = (long long)N_NODE * 64 * (f32_host ? 8 : 4);
    float* fsmall  = (float*)tailbase;
    float* rel   = fsmall;
    float* t1    = rel  + BE;
    float* sess  = t1   + BE;
    float* sessT = sess + BE;
    float* z1p   = sessT + BE;     // slot retained (unused)
    float* z2p   = z1p  + BE;
    float* z2pT  = z2p  + BE;
    float* ns    = z2pT + BE;
    float* n1    = ns + BATCH;     // slot retained (unused)
    float* n2    = n1 + BATCH;
    float* lacc  = n2 + BATCH;
    int*   done2 = (int*)(lacc + 1);
    long long fsmall_bytes = ((char*)(done2 + 16)) - (char*)tailbase;
    long long base_off = tailbase - (char*)d_ws;
    long long need_pad = base_off + (embpad_bytes > fsmall_bytes ? embpad_bytes : fsmall_bytes);
    int use_pad = known_dtype && ((long long)ws_size >= need_pad);
    int estride = use_pad ? 64 : 50;

    // ---- CSR build: one persistent kernel (hist+repack | scan | permute) ----
    hipMemsetAsync(d_ws, 0, 256 + (size_t)N_NODE * sizeof(int), stream);
    csr_build<<<CSR_BLOCKS, 256, 0, stream>>>(arow, acol, aval, counts, bc, cv,
                                              flag, gtot, bar, emb, emb_pad,
                                              f32_host, use_pad);

    // ---- HyperConv via gather (wave per row; 256B-aligned padded rows) ----
    if (use_pad) {
        spmm_gather1<<<(N_NODE + 3) / 4, 256, 0, stream>>>(bc, cv, emb_pad, estride,
                                                           h1buf, flag);
    } else {
        spmm_gather1<<<(N_NODE + 3) / 4, 256, 0, stream>>>(bc, cv, emb, estride,
                                                           h1buf, flag);
    }
    spmm_gather2<<<(N_NODE + 3) / 4, 256, 0, stream>>>(bc, cv, emb, h1buf,
                                                       d_out, flag);

    // ---- everything downstream in one persistent kernel ----
    downstream<<<DS_BLOCKS, 256, 0, stream>>>(
        d_out, items, slen, rel, Amat, t1,
        z2, Wkg1, bkg1, Wkg2, bkg2, z2p, z2pT, n2,
        Dmat, sess, sessT, ns,
        Wcf1, bcf1, Wcf2, bcf2, lacc, done2, bar, flag);
}

// Round 7
// 654.307 us; speedup vs baseline: 3.3026x; 3.3026x over previous
//
#include <hip/hip_runtime.h>
#include <hip/hip_bf16.h>

#define N_NODE 200000
#define EMB 100
#define NNZ 1000000
#define BATCH 1024
#define SLEN 50
#define BE (BATCH * EMB)
#define SCAN_BLK 1024
#define PROJ_ROWS 8
#define UNR 8
#define HIST_BLOCKS 977        // ceil((NNZ/4)/256)
#define REPACK_BLOCKS 12500    // N_NODE*16/256  (4 pairs/thread)

#define OFF_LC    20000000LL
#define OFF_NB    20102400LL
#define OFF_LOSS  20204800LL

typedef __hip_bfloat16 bf16;

__device__ __forceinline__ float b2f(bf16 x) { return __bfloat162float(x); }
__device__ __forceinline__ bf16 f2b(float x) { return __float2bfloat16(x); }

__device__ __forceinline__ float ldf(const void* p, long long i, int f32) {
    return f32 ? ((const float*)p)[i] : b2f(((const bf16*)p)[i]);
}
__device__ __forceinline__ void stf(void* p, long long i, int f32, float v) {
    if (f32) ((float*)p)[i] = v;
    else     ((bf16*)p)[i] = f2b(v);
}

// ---- paired (2-element) helpers: pair index pi covers elements 2pi, 2pi+1 ----
__device__ __forceinline__ float bfb2f(unsigned short s) {
    return __uint_as_float(((unsigned)s) << 16);
}
__device__ __forceinline__ unsigned short f2bfb(float x) {
    bf16 h = f2b(x); unsigned short r; __builtin_memcpy(&r, &h, 2); return r;
}
__device__ __forceinline__ float2 up2(unsigned u) {
    return make_float2(bfb2f((unsigned short)(u & 0xffff)), bfb2f((unsigned short)(u >> 16)));
}
__device__ __forceinline__ unsigned pk2(float a, float b) {
    return (unsigned)f2bfb(a) | ((unsigned)f2bfb(b) << 16);
}
__device__ __forceinline__ float2 ldf2(const void* p, long long pi, int f32) {
    if (f32) return ((const float2*)p)[pi];
    return up2(((const unsigned*)p)[pi]);
}
template<bool F32>
__device__ __forceinline__ float2 ldf2t(const void* p, long long pi) {
    if (F32) return ((const float2*)p)[pi];
    return up2(((const unsigned*)p)[pi]);
}
__device__ __forceinline__ void stf2(void* p, long long pi, int f32, float a, float b) {
    if (f32) ((float2*)p)[pi] = make_float2(a, b);
    else     ((unsigned*)p)[pi] = pk2(a, b);
}

__device__ __forceinline__ float wave_allreduce_sum(float v) {
    for (int m = 32; m > 0; m >>= 1) v += __shfl_xor(v, m, 64);
    return v;
}

// ================= CSR build =================
// hist (4 edges/thread, int4 loads) + dtype sniff + appended repack-emb blocks
__global__ void hist_repack(const int* __restrict__ rows, int* __restrict__ counts,
                            const void* __restrict__ adjval, int* __restrict__ flag,
                            const void* __restrict__ emb, void* __restrict__ embp,
                            int f32h) {
    if (blockIdx.x == 0 && threadIdx.x == 0) {
        int f = 0;
        const bf16* p = (const bf16*)adjval;
        for (int i = 0; i < 64; i++) {
            float x = b2f(p[i]);
            if (!(x >= 0.0f && x <= 1.0f)) f = 1;
        }
        *flag = f;
    }
    if (blockIdx.x < HIST_BLOCKS) {
        int e0 = (blockIdx.x * 256 + threadIdx.x) * 4;
        if (e0 < NNZ) {
            int4 r4 = *(const int4*)&rows[e0];
            atomicAdd(&counts[r4.x], 1);
            atomicAdd(&counts[r4.y], 1);
            atomicAdd(&counts[r4.z], 1);
            atomicAdd(&counts[r4.w], 1);
        }
        return;
    }
    // repack emb rows (50 pairs) into 64-pair padded aligned rows, 4 pairs/thread
    long long idx = (long long)(blockIdx.x - HIST_BLOCKS) * 256 + threadIdx.x;
    if (idx >= (long long)N_NODE * 16) return;
    long long r = idx >> 4;
    int l0 = (int)(idx & 15) * 4;
    #pragma unroll
    for (int j = 0; j < 4; j++) {
        int l = l0 + j;
        float2 v = make_float2(0.f, 0.f);
        if (l < 50) v = ldf2(emb, r * 50 + l, f32h);
        stf2(embp, r * 64 + l, f32h, v.x, v.y);
    }
}

// one-pass scan: block-local inclusive scan + atomic block base.
// Row ranges are disjoint but NOT monotonic across blocks -- spmm uses (base,count).
__global__ void scan_base(const int* __restrict__ counts, int* __restrict__ cursor,
                          int2* __restrict__ bc, int* __restrict__ gtot) {
    __shared__ int s[SCAN_BLK];
    __shared__ int basesh;
    int i = blockIdx.x * SCAN_BLK + threadIdx.x;
    int v = (i < N_NODE) ? counts[i] : 0;
    s[threadIdx.x] = v;
    __syncthreads();
    for (int off = 1; off < SCAN_BLK; off <<= 1) {
        int add = (threadIdx.x >= (unsigned)off) ? s[threadIdx.x - off] : 0;
        __syncthreads();
        s[threadIdx.x] += add;
        __syncthreads();
    }
    if (threadIdx.x == SCAN_BLK - 1) basesh = atomicAdd(gtot, s[threadIdx.x]);
    __syncthreads();
    if (i < N_NODE) {
        int ex = s[threadIdx.x] - v + basesh;
        cursor[i] = ex;           // cursor aliases counts: read-before-write per thread
        bc[i] = make_int2(ex, v);
    }
}

// packed (col, val_bits) per edge (1 edge/thread); also zero the +8 pad entries
__global__ void permute_edges(const int* __restrict__ arow, const int* __restrict__ acol,
                              const void* __restrict__ aval, int* __restrict__ cursor,
                              int2* __restrict__ cv, const int* __restrict__ flagp) {
    const int f32 = *flagp;
    int e = blockIdx.x * 256 + threadIdx.x;
    if (blockIdx.x == 0 && threadIdx.x < 8) cv[NNZ + threadIdx.x] = make_int2(0, 0);
    if (e >= NNZ) return;
    int r = arow[e];
    int pos = atomicAdd(&cursor[r], 1);
    float v = ldf(aval, e, f32);
    cv[pos] = make_int2(acol[e], __float_as_int(v));
}

// ================= SpMM: wave per row, vectorizable cv loads =================
__device__ __forceinline__ void ld_cv8(int2* c, const int2* __restrict__ cv, int k0) {
    #pragma unroll
    for (int j = 0; j < UNR; j++) c[j] = cv[k0 + j];   // unconditional, mergeable
}

template<bool F32>
__device__ __forceinline__ void spmm1_body(
        const int2* __restrict__ bc, const int2* __restrict__ cv,
        const void* __restrict__ src, int estride, unsigned* __restrict__ h1) {
    int lane = threadIdx.x & 63;
    int r = blockIdx.x * 4 + (threadIdx.x >> 6);
    if (r >= N_NODE) return;
    bool act = lane < 50;
    int pl = (estride == 64) ? lane : (act ? lane : 0);
    int2 b = bc[r];
    int k0 = b.x, k1 = b.x + b.y;
    int2 c[UNR];
    ld_cv8(c, cv, k0);
    int c0x = c[0].x;
    float2 e[UNR];
    #pragma unroll
    for (int j = 0; j < UNR; j++) {
        int cl = (k0 + j < k1) ? c[j].x : c0x;       // clamp in registers, same line
        e[j] = ldf2t<F32>(src, (long long)cl * estride + pl);
    }
    float a0 = 0.f, a1 = 0.f;
    #pragma unroll
    for (int j = 0; j < UNR; j++) {
        float v = (k0 + j < k1) ? __int_as_float(c[j].y) : 0.f;
        a0 += v * e[j].x; a1 += v * e[j].y;
    }
    for (int k = k0 + UNR; k < k1; k += UNR) {       // rare tail (deg > 8)
        int2 ct[UNR];
        #pragma unroll
        for (int j = 0; j < UNR; j++) { int kk = k + j; ct[j] = cv[kk < k1 ? kk : k1 - 1]; }
        float2 et[UNR];
        #pragma unroll
        for (int j = 0; j < UNR; j++)
            et[j] = ldf2t<F32>(src, (long long)ct[j].x * estride + pl);
        #pragma unroll
        for (int j = 0; j < UNR; j++) {
            float v = (k + j < k1) ? __int_as_float(ct[j].y) : 0.f;
            a0 += v * et[j].x; a1 += v * et[j].y;
        }
    }
    h1[(long long)r * 64 + lane] = pk2(a0, a1);      // full-wave 256B aligned store
}

__global__ __launch_bounds__(256) void spmm_gather1(
        const int2* __restrict__ bc, const int2* __restrict__ cv,
        const void* __restrict__ src, int estride,
        unsigned* __restrict__ h1, const int* __restrict__ flagp) {
    if (*flagp) spmm1_body<true>(bc, cv, src, estride, h1);
    else        spmm1_body<false>(bc, cv, src, estride, h1);
}

template<bool F32>
__device__ __forceinline__ void spmm2_body(
        const int2* __restrict__ bc, const int2* __restrict__ cv,
        const void* __restrict__ src2, int estride2,
        const unsigned* __restrict__ h1, void* __restrict__ out) {
    int lane = threadIdx.x & 63;
    int r = blockIdx.x * 4 + (threadIdx.x >> 6);
    if (r >= N_NODE) return;
    bool act = lane < 50;
    int pl = act ? lane : 0;
    int pl2 = (estride2 == 64) ? lane : pl;          // padded: aligned full-wave read
    int2 b = bc[r];
    int k0 = b.x, k1 = b.x + b.y;
    int2 c[UNR];
    ld_cv8(c, cv, k0);
    int c0x = c[0].x;
    float2 ebv = ldf2t<F32>(src2, (long long)r * estride2 + pl2);
    float2 h1r = up2(h1[(long long)r * 64 + lane]);
    float2 e[UNR];
    #pragma unroll
    for (int j = 0; j < UNR; j++) {
        int cl = (k0 + j < k1) ? c[j].x : c0x;
        e[j] = up2(h1[(long long)cl * 64 + lane]);   // padded aligned gather
    }
    float a0 = 0.f, a1 = 0.f;
    #pragma unroll
    for (int j = 0; j < UNR; j++) {
        float v = (k0 + j < k1) ? __int_as_float(c[j].y) : 0.f;
        a0 += v * e[j].x; a1 += v * e[j].y;
    }
    for (int k = k0 + UNR; k < k1; k += UNR) {       // rare tail
        int2 ct[UNR];
        #pragma unroll
        for (int j = 0; j < UNR; j++) { int kk = k + j; ct[j] = cv[kk < k1 ? kk : k1 - 1]; }
        float2 et[UNR];
        #pragma unroll
        for (int j = 0; j < UNR; j++)
            et[j] = up2(h1[(long long)ct[j].x * 64 + lane]);
        #pragma unroll
        for (int j = 0; j < UNR; j++) {
            float v = (k + j < k1) ? __int_as_float(ct[j].y) : 0.f;
            a0 += v * et[j].x; a1 += v * et[j].y;
        }
    }
    if (act)
        stf2(out, (long long)r * 50 + lane, F32 ? 1 : 0,
             (ebv.x + h1r.x + a0) * (1.0f / 3.0f), (ebv.y + h1r.y + a1) * (1.0f / 3.0f));
}

__global__ __launch_bounds__(256) void spmm_gather2(
        const int2* __restrict__ bc, const int2* __restrict__ cv,
        const void* __restrict__ src2, int estride2,
        const unsigned* __restrict__ h1, void* __restrict__ out,
        const int* __restrict__ flagp) {
    if (*flagp) spmm2_body<true>(bc, cv, src2, estride2, h1, out);
    else        spmm2_body<false>(bc, cv, src2, estride2, h1, out);
}

// ================= downstream =================
template<bool F32>
__device__ __forceinline__ void rel_rows_body(
        const void* __restrict__ out, const int* __restrict__ items,
        const void* __restrict__ slen, float* __restrict__ rel) {
    int lane = threadIdx.x & 63;
    int b = blockIdx.x * 4 + (threadIdx.x >> 6);
    if (b >= BATCH || lane >= 50) return;
    float s0 = 0.f, s1 = 0.f;
    #pragma unroll
    for (int l0 = 0; l0 < SLEN; l0 += 10) {
        int it[10];
        #pragma unroll
        for (int j = 0; j < 10; j++) it[j] = items[b * SLEN + l0 + j];
        float2 e[10];
        #pragma unroll
        for (int j = 0; j < 10; j++) {
            int idx = (it[j] > 0) ? it[j] - 1 : 0;
            e[j] = ldf2t<F32>(out, (long long)idx * 50 + lane);
        }
        #pragma unroll
        for (int j = 0; j < 10; j++) {
            float m = (it[j] > 0) ? 1.f : 0.f;
            s0 += m * e[j].x; s1 += m * e[j].y;
        }
    }
    float inv = 1.0f / ldf(slen, b, F32 ? 1 : 0);
    ((float2*)rel)[b * 50 + lane] = make_float2(s0 * inv, s1 * inv);
}

__global__ __launch_bounds__(256) void rel_rows(
        const void* __restrict__ out, const int* __restrict__ items,
        const void* __restrict__ slen, float* __restrict__ rel,
        const int* __restrict__ flagp) {
    if (*flagp) rel_rows_body<true>(out, items, slen, rel);
    else        rel_rows_body<false>(out, items, slen, rel);
}

// ---- shared device bodies for fused kernels ----
__device__ __forceinline__ void bmm0_dev(float* smem, const void* __restrict__ M,
                                         const float* __restrict__ X, float* __restrict__ Y,
                                         int f32, int blk) {
    float (*ms)[BATCH] = (float(*)[BATCH])smem;
    int i0 = blk * 4;
    int t = threadIdx.x;
    for (int idx = t; idx < 2 * BATCH; idx += 256) {       // pair loads: 4 rows x 512
        int rr = idx >> 9, j2 = idx & 511;
        float2 v = ldf2(M, (long long)(i0 + rr) * (BATCH / 2) + j2, f32);
        ms[rr][2 * j2] = v.x;
        ms[rr][2 * j2 + 1] = v.y;
    }
    __syncthreads();
    int w = t >> 6, lane = t & 63;
    if (lane >= 50) return;
    int i = i0 + w;
    const float2* X2 = (const float2*)X;
    float s0 = 0.f, s1 = 0.f;
    for (int j = 0; j < BATCH; j++) {
        float m = ms[w][j];
        float2 x = X2[j * 50 + lane];
        s0 += m * x.x; s1 += m * x.y;
    }
    ((float2*)Y)[i * 50 + lane] = make_float2(s0, s1);
}

// fused projector body: Z = (ELU(X@W1^T+b1))@W2^T+b2, plus row norm, opt transpose
__device__ void proj_dev(float* smem, const void* __restrict__ X, int x_dual,
                         const void* __restrict__ W1, const void* __restrict__ B1,
                         const void* __restrict__ W2, const void* __restrict__ B2,
                         float* __restrict__ Z, float* __restrict__ ZT,
                         float* __restrict__ nrm, int f32, int blk) {
    float* wT = smem;                               // 10000
    float* bsh = smem + 10000;                      // 100
    float (*hid)[EMB] = (float(*)[EMB])(smem + 10100);  // 800
    float (*xr)[EMB]  = (float(*)[EMB])(smem + 10900);  // 200
    float (*red2)[2]  = (float(*)[2])(smem + 11100);    // 4
    int t = threadIdx.x;
    int sub = t >> 7, u = t & 127;
    int r0 = blk * PROJ_ROWS;
    // ---- phase A: layer 1 ----
    for (int idx = t; idx < EMB * EMB; idx += 256) {
        int o = idx / EMB, k = idx - o * EMB;
        wT[k * EMB + o] = ldf(W1, idx, f32);
    }
    if (t < EMB) bsh[t] = ldf(B1, t, f32);
    __syncthreads();
    for (int pr = 0; pr < PROJ_ROWS; pr += 2) {
        int row = r0 + pr + sub;
        if (u < EMB)
            xr[sub][u] = x_dual ? ldf(X, (long long)row * EMB + u, f32)
                                : ((const float*)X)[row * EMB + u];
        __syncthreads();
        if (u < EMB) {
            float s = bsh[u];
            for (int k = 0; k < EMB; k++) s += xr[sub][k] * wT[k * EMB + u];
            hid[pr + sub][u] = (s > 0.f) ? s : expm1f(s);
        }
        __syncthreads();
    }
    // ---- phase B: layer 2 + norm ----
    for (int idx = t; idx < EMB * EMB; idx += 256) {
        int o = idx / EMB, k = idx - o * EMB;
        wT[k * EMB + o] = ldf(W2, idx, f32);
    }
    if (t < EMB) bsh[t] = ldf(B2, t, f32);
    __syncthreads();
    for (int pr = 0; pr < PROJ_ROWS; pr += 2) {
        int row = r0 + pr + sub;
        float sq = 0.f;
        if (u < EMB) {
            float o = bsh[u];
            const float* h = hid[pr + sub];
            for (int k = 0; k < EMB; k++) o += h[k] * wT[k * EMB + u];
            Z[(long long)row * EMB + u] = o;
            if (ZT) ZT[(long long)u * BATCH + row] = o;
            sq = o * o;
        }
        sq = wave_allreduce_sum(sq);
        if ((t & 63) == 0) red2[sub][(t >> 6) & 1] = sq;
        __syncthreads();
        if (u == 0) nrm[row] = sqrtf(red2[sub][0] + red2[sub][1]);
        __syncthreads();
    }
}

// projector for z1 (sess, f32) fused with its 8 loss rows; z1p/n1 stay in LDS
__device__ void proj_loss_dev(float* smem, const float* __restrict__ X,
                              const void* __restrict__ W1, const void* __restrict__ B1,
                              const void* __restrict__ W2, const void* __restrict__ B2,
                              const float* __restrict__ z2pT, const float* __restrict__ n2,
                              float* __restrict__ lacc, int* __restrict__ done,
                              void* __restrict__ out, int f32, int blk) {
    float* wT = smem;                               // 10000
    float* bsh = smem + 10000;                      // 100
    float (*hid)[EMB] = (float(*)[EMB])(smem + 10100);  // 800
    float (*xr)[EMB]  = (float(*)[EMB])(smem + 10900);  // 200
    float (*red2)[2]  = (float(*)[2])(smem + 11100);    // 4
    float (*zsh)[EMB] = (float(*)[EMB])(smem + 11104);  // 800
    float* n1sh = smem + 11904;                     // 8
    float* sd   = smem + 11912;                     // 1
    float* red  = smem + 11913;                     // 4
    int t = threadIdx.x;
    int sub = t >> 7, u = t & 127;
    int r0 = blk * PROJ_ROWS;
    // ---- phase A ----
    for (int idx = t; idx < EMB * EMB; idx += 256) {
        int o = idx / EMB, k = idx - o * EMB;
        wT[k * EMB + o] = ldf(W1, idx, f32);
    }
    if (t < EMB) bsh[t] = ldf(B1, t, f32);
    __syncthreads();
    for (int pr = 0; pr < PROJ_ROWS; pr += 2) {
        int row = r0 + pr + sub;
        if (u < EMB) xr[sub][u] = X[(long long)row * EMB + u];
        __syncthreads();
        if (u < EMB) {
            float s = bsh[u];
            for (int k = 0; k < EMB; k++) s += xr[sub][k] * wT[k * EMB + u];
            hid[pr + sub][u] = (s > 0.f) ? s : expm1f(s);
        }
        __syncthreads();
    }
    // ---- phase B: layer 2 + norm, keep rows in LDS ----
    for (int idx = t; idx < EMB * EMB; idx += 256) {
        int o = idx / EMB, k = idx - o * EMB;
        wT[k * EMB + o] = ldf(W2, idx, f32);
    }
    if (t < EMB) bsh[t] = ldf(B2, t, f32);
    __syncthreads();
    for (int pr = 0; pr < PROJ_ROWS; pr += 2) {
        float sq = 0.f;
        float o = 0.f;
        if (u < EMB) {
            o = bsh[u];
            const float* h = hid[pr + sub];
            for (int k = 0; k < EMB; k++) o += h[k] * wT[k * EMB + u];
            sq = o * o;
        }
        __syncthreads();              // all reads of hid[pr+sub] done
        if (u < EMB) zsh[pr + sub][u] = o;
        sq = wave_allreduce_sum(sq);
        if ((t & 63) == 0) red2[sub][(t >> 6) & 1] = sq;
        __syncthreads();
        if (u == 0) n1sh[pr + sub] = sqrtf(red2[sub][0] + red2[sub][1]);
        __syncthreads();
    }
    // ---- loss for the 8 rows ----
    float blockloss = 0.f;
    for (int rr = 0; rr < PROJ_ROWS; rr++) {
        int i = r0 + rr;
        float ni = n1sh[rr];
        float d0 = 0.f, d1 = 0.f, d2 = 0.f, d3 = 0.f;
        for (int k = 0; k < EMB; k++) {
            float zv = zsh[rr][k];
            const float* row = z2pT + k * BATCH;
            d0 += zv * row[t];
            d1 += zv * row[t + 256];
            d2 += zv * row[t + 512];
            d3 += zv * row[t + 768];
        }
        float e0 = expf(d0 / (ni * n2[t]) * 5.0f);
        float e1 = expf(d1 / (ni * n2[t + 256]) * 5.0f);
        float e2 = expf(d2 / (ni * n2[t + 512]) * 5.0f);
        float e3 = expf(d3 / (ni * n2[t + 768]) * 5.0f);
        if (t == (i & 255)) {
            int m = i >> 8;
            sd[0] = (m == 0) ? e0 : (m == 1) ? e1 : (m == 2) ? e2 : e3;
        }
        float local = e0 + e1 + e2 + e3;
        float w = wave_allreduce_sum(local);
        if ((t & 63) == 0) red[t >> 6] = w;
        __syncthreads();
        if (t == 0) {
            float S = red[0] + red[1] + red[2] + red[3];
            blockloss += -logf(sd[0] / (S + 1e-8f));
        }
        __syncthreads();
    }
    if (t == 0) {
        atomicAdd(lacc, blockloss * (1.0f / BATCH));
        __threadfence();
        int old = atomicAdd(done, 1);
        if (old == BATCH / PROJ_ROWS - 1) {
            float v = atomicAdd(lacc, 0.0f);   // fully-merged value
            stf(out, OFF_LOSS, f32, v);
        }
    }
}

// blocks 0..255: bmm1 (A@rel -> t1). blocks 256..383: proj(z2) -> z2p,z2pT,n2
__global__ __launch_bounds__(256) void bmm1_projz2(
        const void* __restrict__ A, const float* __restrict__ relv, float* __restrict__ t1,
        const void* __restrict__ z2,
        const void* __restrict__ W1, const void* __restrict__ B1,
        const void* __restrict__ W2, const void* __restrict__ B2,
        float* __restrict__ z2p, float* __restrict__ z2pT, float* __restrict__ n2,
        const int* __restrict__ flagp) {
    __shared__ float smem[11104];
    const int f32 = *flagp;
    if (blockIdx.x < 256) bmm0_dev(smem, A, relv, t1, f32, blockIdx.x);
    else proj_dev(smem, z2, 1, W1, B1, W2, B2, z2p, z2pT, n2, f32, blockIdx.x - 256);
}

// bmm2 fused with selu + L2-normalize; block 0 also zeroes loss accumulators
__global__ __launch_bounds__(256) void bmm2_selu(const void* __restrict__ M,
                                                 const float* __restrict__ X,
                                                 float* __restrict__ sess,
                                                 float* __restrict__ sessT,
                                                 float* __restrict__ ns,
                                                 void* __restrict__ out,
                                                 float* __restrict__ lacc,
                                                 int* __restrict__ done,
                                                 const int* __restrict__ flagp) {
    __shared__ float ms[4][BATCH];
    const int f32 = *flagp;
    if (blockIdx.x == 0 && threadIdx.x == 0) { *lacc = 0.f; *done = 0; }
    int i0 = blockIdx.x * 4;
    int t = threadIdx.x;
    for (int idx = t; idx < 2 * BATCH; idx += 256) {       // pair loads: 4 rows x 512
        int rr = idx >> 9, j2 = idx & 511;
        float2 v = ldf2(M, (long long)(i0 + rr) * (BATCH / 2) + j2, f32);
        ms[rr][2 * j2] = v.x;
        ms[rr][2 * j2 + 1] = v.y;
    }
    __syncthreads();
    int w = t >> 6, lane = t & 63;
    bool act = lane < 50;
    int i = i0 + w;
    float s0 = 0.f, s1 = 0.f;
    if (act) {
        const float2* X2 = (const float2*)X;
        for (int j = 0; j < BATCH; j++) {
            float m = ms[w][j];
            float2 x = X2[j * 50 + lane];
            s0 += m * x.x; s1 += m * x.y;
        }
    }
    const float sc = 1.0507009873554804934193349852946f;
    const float al = 1.6732632423543772848170429916717f;
    float c0 = (s0 > 0.f) ? sc * s0 : sc * (al * expm1f(s0));
    float c1 = (s1 > 0.f) ? sc * s1 : sc * (al * expm1f(s1));
    if (!act) { c0 = 0.f; c1 = 0.f; }
    float nrm = sqrtf(wave_allreduce_sum(c0 * c0 + c1 * c1));
    float l0 = c0 / nrm, l1 = c1 / nrm;
    float nterm = act ? (l0 * l0 + l1 * l1 + 2e-6f) : 0.f;
    float n2sum = wave_allreduce_sum(nterm);
    if (act) {
        ((float2*)sess)[i * 50 + lane] = make_float2(l0, l1);
        sessT[(2 * lane) * BATCH + i] = l0;
        sessT[(2 * lane + 1) * BATCH + i] = l1;
        stf2(out, OFF_LC / 2 + (long long)i * 50 + lane, f32, l0, l1);
    }
    if (lane == 0) ns[i] = sqrtf(n2sum);
}

__device__ void neighbor_dev(float* smem, const float* __restrict__ sess,
                             const float* __restrict__ sessT, const float* __restrict__ ns,
                             void* __restrict__ out, int f32, int i) {
    float* si  = smem;                 // 100
    float* red = smem + 100;           // 4
    float* wrv = smem + 104;           // 4
    int*   wri = (int*)(smem + 108);   // 4
    float* chv = smem + 112;           // 3
    int*   chi = (int*)(smem + 115);   // 3
    float* stv = smem + 118;           // 3
    int t = threadIdx.x;   // 256 threads
    if (t < EMB) si[t] = sess[i * EMB + t];
    __syncthreads();
    float ni = ns[i];
    float d0 = 0.f, d1 = 0.f, d2 = 0.f, d3 = 0.f;
    for (int k = 0; k < EMB; k++) {
        float sv = si[k];
        const float* row = sessT + k * BATCH;
        d0 += sv * row[t];
        d1 += sv * row[t + 256];
        d2 += sv * row[t + 512];
        d3 += sv * row[t + 768];
    }
    float pv0 = expf(d0 / (ni * ns[t]));
    float pv1 = expf(d1 / (ni * ns[t + 256]));
    float pv2 = expf(d2 / (ni * ns[t + 512]));
    float pv3 = expf(d3 / (ni * ns[t + 768]));
    float local = pv0 + pv1 + pv2 + pv3;
    float w = wave_allreduce_sum(local);
    if ((t & 63) == 0) red[t >> 6] = w;
    __syncthreads();
    float S = red[0] + red[1] + red[2] + red[3];

    int c0 = -1, c1 = -1, c2 = -1;
    float pv[4] = {pv0, pv1, pv2, pv3};
    for (int r = 0; r < 3; r++) {
        float bv = -1e30f; int bi = 0x7fffffff;
        #pragma unroll
        for (int m = 0; m < 4; m++) {
            int j = t + (m << 8);
            if (j == c0 || j == c1 || j == c2) continue;
            float v = pv[m];
            if (v > bv || (v == bv && j < bi)) { bv = v; bi = j; }
        }
        #pragma unroll
        for (int off = 1; off < 64; off <<= 1) {
            float ov = __shfl_xor(bv, off);
            int oi = __shfl_xor(bi, off);
            if (ov > bv || (ov == bv && oi < bi)) { bv = ov; bi = oi; }
        }
        if ((t & 63) == 0) { wrv[t >> 6] = bv; wri[t >> 6] = bi; }
        __syncthreads();
        if (t == 0) {
            float fv = wrv[0]; int fi = wri[0];
            for (int wq = 1; wq < 4; wq++) {
                if (wrv[wq] > fv || (wrv[wq] == fv && wri[wq] < fi)) { fv = wrv[wq]; fi = wri[wq]; }
            }
            chv[r] = fv; chi[r] = fi;
        }
        __syncthreads();
        if (r == 0) c0 = chi[0];
        else if (r == 1) c1 = chi[1];
        else c2 = chi[2];
    }
    if (t == 0) {
        float e0 = expf(chv[0] / S), e1 = expf(chv[1] / S), e2 = expf(chv[2] / S);
        float es = e0 + e1 + e2;
        stv[0] = e0 / es; stv[1] = e1 / es; stv[2] = e2 / es;
    }
    __syncthreads();
    if (t < EMB) {
        float o = stv[0] * sess[chi[0] * EMB + t]
                + stv[1] * sess[chi[1] * EMB + t]
                + stv[2] * sess[chi[2] * EMB + t];
        stf(out, OFF_NB + i * EMB + t, f32, o);
    }
}

// blocks 0..1023: FindNeighbors; blocks 1024..1151: proj(sess)+loss (fused final)
__global__ __launch_bounds__(256) void neighbor_projz1_loss(
        const float* __restrict__ sess, const float* __restrict__ sessT,
        const float* __restrict__ ns, void* __restrict__ out,
        const void* __restrict__ W1, const void* __restrict__ B1,
        const void* __restrict__ W2, const void* __restrict__ B2,
        const float* __restrict__ z2pT, const float* __restrict__ n2,
        float* __restrict__ lacc, int* __restrict__ done,
        const int* __restrict__ flagp) {
    __shared__ float smem[11920];
    const int f32 = *flagp;
    if (blockIdx.x < BATCH) neighbor_dev(smem, sess, sessT, ns, out, f32, blockIdx.x);
    else proj_loss_dev(smem, sess, W1, B1, W2, B2, z2pT, n2, lacc, done, out, f32,
                       blockIdx.x - BATCH);
}

extern "C" void kernel_launch(void* const* d_in, const int* in_sizes, int n_in,
                              void* d_out, int out_size, void* d_ws, size_t ws_size,
                              hipStream_t stream) {
    const void* emb  = d_in[0];
    const void* aval = d_in[1];
    const void* Amat = d_in[2];
    const void* Dmat = d_in[3];
    const void* z2   = d_in[4];
    const void* Wcf1 = d_in[5];
    const void* bcf1 = d_in[6];
    const void* Wcf2 = d_in[7];
    const void* bcf2 = d_in[8];
    const void* Wkg1 = d_in[9];
    const void* bkg1 = d_in[10];
    const void* Wkg2 = d_in[11];
    const void* bkg2 = d_in[12];
    const void* slen = d_in[13];
    const int* arow  = (const int*)d_in[14];
    const int* acol  = (const int*)d_in[15];
    const int* items = (const int*)d_in[16];

    // dtype from host-visible byte size (exact match only; else no padding)
    long long esz = in_sizes ? (long long)in_sizes[0] : 0;
    int f32_host = (esz == (long long)N_NODE * EMB * 4) ? 1 : 0;
    int known_dtype = (esz == (long long)N_NODE * EMB * 2) || f32_host;

    // ---- workspace layout ----
    int* flag      = (int*)d_ws;
    int* gtot      = (int*)d_ws + 4;
    int* counts    = (int*)((char*)d_ws + 256);        // N_NODE (aliased as cursor)
    int* cursor    = counts;
    int2* bc       = (int2*)(counts + N_NODE);         // N_NODE (base,count)
    int2* cv       = bc + N_NODE;                      // NNZ+8 packed (col,val)
    unsigned* h1buf = (unsigned*)(cv + NNZ + 8);       // N_NODE*64 pairs, padded (51.2MB)
    char* tailbase = (char*)(h1buf + (long long)N_NODE * 64);
    // emb_pad (live during repack+spmm1+spmm2) aliases the small-buffer region
    void* emb_pad  = (void*)tailbase;
    long long embpad_bytes = (long long)N_NODE * 64 * (f32_host ? 8 : 4);
    float* fsmall  = (float*)tailbase;
    float* rel   = fsmall;
    float* t1    = rel  + BE;
    float* sess  = t1   + BE;
    float* sessT = sess + BE;
    float* z1p   = sessT + BE;     // slot retained (unused)
    float* z2p   = z1p  + BE;
    float* z2pT  = z2p  + BE;
    float* ns    = z2pT + BE;
    float* n1    = ns + BATCH;     // slot retained (unused)
    float* n2    = n1 + BATCH;
    float* lacc  = n2 + BATCH;
    int*   done  = (int*)(lacc + 1);
    long long fsmall_bytes = ((char*)(done + 16)) - (char*)tailbase;
    long long base_off = tailbase - (char*)d_ws;
    long long need_pad = base_off + (embpad_bytes > fsmall_bytes ? embpad_bytes : fsmall_bytes);
    int use_pad = known_dtype && ((long long)ws_size >= need_pad);
    int estride = use_pad ? 64 : 50;

    const int nscan = (N_NODE + SCAN_BLK - 1) / SCAN_BLK;
    const int repack_blocks = use_pad ? REPACK_BLOCKS : 0;

    // ---- CSR build (repack hidden under hist; one-pass scan w/ atomic bases) ----
    hipMemsetAsync(d_ws, 0, 256 + (size_t)N_NODE * sizeof(int), stream);
    hist_repack<<<HIST_BLOCKS + repack_blocks, 256, 0, stream>>>(
        arow, counts, aval, flag, emb, emb_pad, f32_host);
    scan_base<<<nscan, SCAN_BLK, 0, stream>>>(counts, cursor, bc, gtot);
    permute_edges<<<(NNZ + 255) / 256, 256, 0, stream>>>(arow, acol, aval, cursor,
                                                         cv, flag);

    // ---- HyperConv via gather (wave per row; 256B-aligned padded rows) ----
    const void* spmm_src = use_pad ? emb_pad : emb;
    spmm_gather1<<<(N_NODE + 3) / 4, 256, 0, stream>>>(bc, cv, spmm_src, estride,
                                                       h1buf, flag);
    spmm_gather2<<<(N_NODE + 3) / 4, 256, 0, stream>>>(bc, cv, spmm_src, estride,
                                                       h1buf, d_out, flag);

    // ---- RelationGAT + contrast projector (z2) ----
    rel_rows<<<(BATCH + 3) / 4, 256, 0, stream>>>(d_out, items, slen, rel, flag);
    bmm1_projz2<<<384, 256, 0, stream>>>(Amat, rel, t1,
                                         z2, Wkg1, bkg1, Wkg2, bkg2,
                                         z2p, z2pT, n2, flag);
    bmm2_selu<<<BATCH / 4, 256, 0, stream>>>(Dmat, t1, sess, sessT, ns, d_out,
                                             lacc, done, flag);

    // ---- FindNeighbors + contrast projector (z1) + fused loss ----
    neighbor_projz1_loss<<<BATCH + BATCH / PROJ_ROWS, 256, 0, stream>>>(
        sess, sessT, ns, d_out, Wcf1, bcf1, Wcf2, bcf2, z2pT, n2, lacc, done, flag);
}